// Round 1
// baseline (83.745 us; speedup 1.0000x reference)
//
#include <hip/hip_runtime.h>
#include <hip/hip_bf16.h>

#define NT 512

constexpr int B_ = 16, N_ = 64, S_ = 4, F0_ = 8, C_ = 32;

// LDS strides (elements). All chosen so 16-lane frag accesses are <=2-way.
constexpr int ESTR = 72;            // E/A operand rows [t][i]
constexpr int EMAT = N_ * ESTR;     // 4608 elems per 64x64 matrix
constexpr int XSTR = 40;            // X/H operand rows [i][k], K=32
constexpr int WSTR = 40;            // WcatT rows [n][k],  K=32
constexpr int PSTR = 72;            // P transposed rows [n][i], K(i)=64

typedef __attribute__((ext_vector_type(8))) short short8;
typedef __attribute__((ext_vector_type(4))) float f32x4;

// Manual RNE float->bf16 (finite inputs only). Matches __float2bfloat16 RNE
// for normal values with ~3 VALU ops instead of the NaN-guarded sequence.
__device__ __forceinline__ unsigned short f2bf(float x) {
    unsigned int u;
    __builtin_memcpy(&u, &x, 4);
    u += 0x7fffu + ((u >> 16) & 1u);
    return (unsigned short)(u >> 16);
}
__device__ __forceinline__ float bf2f(unsigned short u) {
    unsigned int v = ((unsigned int)u) << 16;
    float f;
    __builtin_memcpy(&f, &v, 4);
    return f;
}
__device__ __forceinline__ void st8(unsigned short* dst, const float* v) {
    union { unsigned short u[8]; short8 s; } p;
#pragma unroll
    for (int j = 0; j < 8; ++j) p.u[j] = f2bf(v[j]);
    *reinterpret_cast<short8*>(dst) = p.s;
}

// Step A: P = H(64xK=32, rows XH) @ Wcat(32x192, given transposed WT[n][k]).
// 8 waves x (1 A-frag read + 6x(B-read + MFMA) + 6 transposed b64 writes).
// Output written bf16-transposed: Pb[n][i] (B-operand form for step B).
__device__ __forceinline__ void stepA(int wv, int lane,
                                      const unsigned short* XHm,
                                      const unsigned short* WT,
                                      unsigned short* Pb) {
    const int l16 = lane & 15, quad = lane >> 4;
    const int mt = wv & 3, nt0 = (wv >> 2) * 6;
    short8 av = *reinterpret_cast<const short8*>(XHm + (mt * 16 + l16) * XSTR + quad * 8);
#pragma unroll
    for (int q = 0; q < 6; ++q) {
        const int nt = nt0 + q;
        short8 bv = *reinterpret_cast<const short8*>(WT + (nt * 16 + l16) * WSTR + quad * 8);
        f32x4 acc = {0.f, 0.f, 0.f, 0.f};
        acc = __builtin_amdgcn_mfma_f32_16x16x32_bf16(av, bv, acc, 0, 0, 0);
        // D[row=i=quad*4+r][col=n=l16] -> Pb[nt*16+l16][mt*16+quad*4+r], 4 consec
        ushort4 pk;
        pk.x = f2bf(acc[0]); pk.y = f2bf(acc[1]);
        pk.z = f2bf(acc[2]); pk.w = f2bf(acc[3]);
        *reinterpret_cast<ushort4*>(Pb + (nt * 16 + l16) * PSTR + mt * 16 + quad * 4) = pk;
    }
}

// Step B core: acc(4) = Sigma_{s=0..4} (M_s @ P_s) tile for wave's (mt,nt).
// M_s = EA[s] (E0..E3, A), P_s = Pb rows [s*32 .. s*32+31]. wv in [0,8).
__device__ __forceinline__ f32x4 stepB_mm(int wv, int lane,
                                          const unsigned short* EA,
                                          const unsigned short* Pb) {
    const int l16 = lane & 15, quad = lane >> 4;
    const int mt = wv >> 1, nt = wv & 1;
    f32x4 acc = {0.f, 0.f, 0.f, 0.f};
#pragma unroll
    for (int s = 0; s < 5; ++s) {
        const unsigned short* ar = EA + s * EMAT + (mt * 16 + l16) * ESTR;
        const unsigned short* br = Pb + (s * 32 + nt * 16 + l16) * PSTR;
#pragma unroll
        for (int kk = 0; kk < 2; ++kk) {
            short8 av = *reinterpret_cast<const short8*>(ar + kk * 32 + quad * 8);
            short8 bv = *reinterpret_cast<const short8*>(br + kk * 32 + quad * 8);
            acc = __builtin_amdgcn_mfma_f32_16x16x32_bf16(av, bv, acc, 0, 0, 0);
        }
    }
    return acc;
}

__global__ __launch_bounds__(NT) void ecc_fused(
    const float* __restrict__ x,  const float* __restrict__ a,  const float* __restrict__ e,
    const float* __restrict__ w1k, const float* __restrict__ b1k,
    const float* __restrict__ w1r, const float* __restrict__ b1v,
    const float* __restrict__ w2k, const float* __restrict__ b2k,
    const float* __restrict__ w2r, const float* __restrict__ b2v,
    const float* __restrict__ wd,  const float* __restrict__ bd,
    float* __restrict__ out)
{
    __shared__ __align__(16) unsigned short EA[5 * EMAT];     // E0..E3, A : 46 KB
    __shared__ __align__(16) unsigned short XH[N_ * XSTR];    // X, then H : 5 KB
    __shared__ __align__(16) unsigned short W1T[192 * WSTR];  // 15 KB
    __shared__ __align__(16) unsigned short W2T[192 * WSTR];  // 15 KB
    __shared__ __align__(16) unsigned short Pb[192 * PSTR];   // 27 KB
    __shared__ float mask_sh[N_];
    __shared__ float b1_sh[C_], b2_sh[C_], wd_sh[C_];
    __shared__ float red_sh[8];

    const int b   = blockIdx.x;
    const int tid = threadIdx.x;
    const int wv  = tid >> 6, lane = tid & 63;
    const float* eb = e + (size_t)b * N_ * N_ * S_;
    const float* ag = a + (size_t)b * N_ * N_;
    const float* xb = x + (size_t)b * N_ * (F0_ + 1);

    // ---- issue E+A loads FIRST; they are consumed only after step A1, so
    //      their HBM/L2 latency hides under the whole weight fold + A1 ----
    float4 ev[8];
    float  av8[8];
#pragma unroll
    for (int r = 0; r < 8; ++r) {
        const int t = wv * 8 + r;
        ev[r]  = *reinterpret_cast<const float4*>(eb + (size_t)(t * N_ + lane) * S_);
        av8[r] = ag[t * N_ + lane];
    }
    const float bd0 = bd[0];   // scalar broadcast load

    // ---- weight fold / x staging: vectorized, row-granular ----
    // x -> XH[t][0..7] + mask (576 scalar reads, coalesced)
    for (int idx = tid; idx < N_ * 9; idx += NT) {
        const int t = idx / 9, j = idx - t * 9;
        const float v = xb[idx];
        if (j == F0_) mask_sh[t] = v;
        else          XH[t * XSTR + j] = f2bf(v);
    }
    // XH K-pad [8,32): 64 rows x 3 ushort8 zeros
    if (tid < 192) {
        const int t = tid / 3, seg = tid - t * 3;
        *reinterpret_cast<short8*>(XH + t * XSTR + 8 + seg * 8) = (short8)0;
    }
    // W1T rows [0,160): w1k/b1k rows are 8 consecutive floats -> 2 x float4
    if (tid < 160) {
        const float* src = (tid < 128) ? (w1k + tid * 8) : (b1k + (tid - 128) * 8);
        const float4 u0 = *reinterpret_cast<const float4*>(src);
        const float4 u1 = *reinterpret_cast<const float4*>(src + 4);
        const float vv[8] = {u0.x, u0.y, u0.z, u0.w, u1.x, u1.y, u1.z, u1.w};
        unsigned short* dst = W1T + tid * WSTR;
        st8(dst, vv);
        *reinterpret_cast<short8*>(dst + 8)  = (short8)0;
        *reinterpret_cast<short8*>(dst + 16) = (short8)0;
        *reinterpret_cast<short8*>(dst + 24) = (short8)0;
    }
    // W2T root rows [160,192): w2r[k][c] transposed via vector row loads
    if (tid < 128) {
        const int k = tid >> 2, cg = (tid & 3) * 8;
        const float4 u0 = *reinterpret_cast<const float4*>(w2r + k * C_ + cg);
        const float4 u1 = *reinterpret_cast<const float4*>(w2r + k * C_ + cg + 4);
        const float vv[8] = {u0.x, u0.y, u0.z, u0.w, u1.x, u1.y, u1.z, u1.w};
#pragma unroll
        for (int j = 0; j < 8; ++j)
            W2T[(160 + cg + j) * WSTR + k] = f2bf(vv[j]);
    }
    // W1T root rows [160,192): w1r[k][c] transposed (k<8)
    if (tid >= 160 && tid < 192) {
        const int c = tid - 160;
        float vv[8];
#pragma unroll
        for (int k = 0; k < 8; ++k) vv[k] = w1r[k * C_ + c];
        unsigned short* dst = W1T + (160 + c) * WSTR;
        st8(dst, vv);
        *reinterpret_cast<short8*>(dst + 8)  = (short8)0;
        *reinterpret_cast<short8*>(dst + 16) = (short8)0;
        *reinterpret_cast<short8*>(dst + 24) = (short8)0;
    }
    // W2T rows [0,160): w2k/b2k rows are 32 consecutive floats; 2 threads/row
    if (tid >= 192) {
        const int i = tid - 192, row = i >> 1, half = i & 1;
        const float* src = ((row < 128) ? (w2k + row * 32) : (b2k + (row - 128) * 32)) + half * 16;
        const float4 u0 = *reinterpret_cast<const float4*>(src);
        const float4 u1 = *reinterpret_cast<const float4*>(src + 4);
        const float4 u2 = *reinterpret_cast<const float4*>(src + 8);
        const float4 u3 = *reinterpret_cast<const float4*>(src + 12);
        const float vv0[8] = {u0.x, u0.y, u0.z, u0.w, u1.x, u1.y, u1.z, u1.w};
        const float vv1[8] = {u2.x, u2.y, u2.z, u2.w, u3.x, u3.y, u3.z, u3.w};
        unsigned short* dst = W2T + row * WSTR + half * 16;
        st8(dst, vv0);
        st8(dst + 8, vv1);
    }
    if (tid < C_) { b1_sh[tid] = b1v[tid]; b2_sh[tid] = b2v[tid]; wd_sh[tid] = wd[tid]; }
    __syncthreads();

    // ---- A1: P1 = X @ Wcat1 (E loads still in flight) ----
    stepA(wv, lane, XH, W1T, Pb);

    // ---- EA convert+store: first use of ev/av8 -> waitcnt lands here ----
#pragma unroll
    for (int r = 0; r < 8; ++r) {
        const int t = wv * 8 + r;
        unsigned short* p = EA + t * ESTR + lane;
        p[0 * EMAT] = f2bf(ev[r].x);
        p[1 * EMAT] = f2bf(ev[r].y);
        p[2 * EMAT] = f2bf(ev[r].z);
        p[3 * EMAT] = f2bf(ev[r].w);
        p[4 * EMAT] = f2bf(av8[r]);
    }
    __syncthreads();

    // ---- B1: h = relu(mask * (Sigma M_s@P_s + P_5 + b1)) -> XH ----
    {
        const int l16 = lane & 15, quad = lane >> 4;
        const int mt = wv >> 1, nt = wv & 1;
        f32x4 acc = stepB_mm(wv, lane, EA, Pb);
        const int c = nt * 16 + l16;
        ushort4 p5 = *reinterpret_cast<const ushort4*>(Pb + (160 + c) * PSTR + mt * 16 + quad * 4);
        const unsigned short p5a[4] = {p5.x, p5.y, p5.z, p5.w};
        const float bc = b1_sh[c];
#pragma unroll
        for (int r = 0; r < 4; ++r) {
            const int t = mt * 16 + quad * 4 + r;
            float v = (acc[r] + bc + bf2f(p5a[r])) * mask_sh[t];
            XH[t * XSTR + c] = f2bf(v > 0.f ? v : 0.f);
        }
    }
    __syncthreads();

    // ---- A2: P2 = H @ Wcat2 ----
    stepA(wv, lane, XH, W2T, Pb);
    __syncthreads();

    // ---- B2: msg2 + fused pool/head ----
    {
        const int l16 = lane & 15, quad = lane >> 4;
        const int mt = wv >> 1, nt = wv & 1;
        f32x4 acc = stepB_mm(wv, lane, EA, Pb);
        const int c = nt * 16 + l16;
        ushort4 p5 = *reinterpret_cast<const ushort4*>(Pb + (160 + c) * PSTR + mt * 16 + quad * 4);
        const unsigned short p5a[4] = {p5.x, p5.y, p5.z, p5.w};
        const float bc = b2_sh[c];
        const float wc = wd_sh[c];
        float partial = 0.f;
#pragma unroll
        for (int r = 0; r < 4; ++r) {
            const int t = mt * 16 + quad * 4 + r;
            float v = (acc[r] + bc + bf2f(p5a[r])) * mask_sh[t];
            partial += (v > 0.f ? v : 0.f) * wc;
        }
#pragma unroll
        for (int off = 32; off > 0; off >>= 1)
            partial += __shfl_down(partial, off, 64);
        if (lane == 0) red_sh[wv] = partial;
    }
    __syncthreads();
    if (tid == 0) {
        float s = bd0;
#pragma unroll
        for (int w = 0; w < 8; ++w) s += red_sh[w];
        out[b] = s;
    }
}

extern "C" void kernel_launch(void* const* d_in, const int* in_sizes, int n_in,
                              void* d_out, int out_size, void* d_ws, size_t ws_size,
                              hipStream_t stream) {
    ecc_fused<<<B_, NT, 0, stream>>>(
        (const float*)d_in[0],  (const float*)d_in[1],  (const float*)d_in[2],
        (const float*)d_in[3],  (const float*)d_in[4],  (const float*)d_in[5],
        (const float*)d_in[6],  (const float*)d_in[7],  (const float*)d_in[8],
        (const float*)d_in[9],  (const float*)d_in[10], (const float*)d_in[11],
        (const float*)d_in[12], (float*)d_out);
}